// Round 5
// baseline (416.797 us; speedup 1.0000x reference)
//
#include <hip/hip_runtime.h>
#include <math.h>
#include <float.h>

// VQVAE forward, MI355X. Round 5: double-buffered glds K-loops (one barrier per
// iter, prefetch hidden behind MFMA), BN=64 variant for GEMM2 (grid 2x), dist
// flattened with cross-chunk prefetch. bf16x3 (hi/mid) MFMA everywhere.

typedef __attribute__((ext_vector_type(8))) short short8;      // MFMA A/B frag
typedef __attribute__((ext_vector_type(4))) float floatx4;     // MFMA C/D frag
typedef __attribute__((ext_vector_type(4))) unsigned short ushort4v;

__device__ __forceinline__ unsigned short f2bf(float f) {
  union { float f; unsigned u; } v; v.f = f;
  unsigned u = v.u;
  return (unsigned short)((u + 0x7FFFu + ((u >> 16) & 1u)) >> 16);
}
__device__ __forceinline__ float bf2f(unsigned short s) {
  union { unsigned u; float f; } v; v.u = ((unsigned)s) << 16;
  return v.f;
}

__device__ __forceinline__ void glds16(const void* g, void* l) {
  __builtin_amdgcn_global_load_lds(
      (const __attribute__((address_space(1))) unsigned int*)g,
      (__attribute__((address_space(3))) unsigned int*)l, 16, 0, 0);
}

__device__ __forceinline__ unsigned packkey(float d, int c) {
  unsigned b = __float_as_uint(d);
  b = (b & 0x80000000u) ? ~b : (b | 0x80000000u);
  return (b & 0xFFFFF800u) | (unsigned)c;
}
__device__ __forceinline__ void ins3(unsigned k, unsigned& v1, unsigned& v2,
                                     unsigned& v3) {
  unsigned t1 = min(v1, k), c1 = max(v1, k);
  unsigned t2 = min(v2, c1), c2 = max(v2, c1);
  v1 = t1; v2 = t2; v3 = min(v3, c2);
}

__global__ __launch_bounds__(256) void conv_pad(
    const float* __restrict__ src, unsigned short* __restrict__ hi,
    unsigned short* __restrict__ mid, int R, int C, int Rp, int Cp) {
  int t = blockIdx.x * 256 + threadIdx.x;
  if (t >= Rp * Cp) return;
  int r = t / Cp, c = t - r * Cp;
  float v = (r < R && c < C) ? src[(long)r * C + c] : 0.f;
  unsigned short h = f2bf(v);
  hi[t] = h;
  mid[t] = f2bf(v - bf2f(h));
}

__global__ __launch_bounds__(256) void emb_norm(const float* __restrict__ emb,
                                                float* __restrict__ enorm) {
  const int gtid = blockIdx.x * 256 + threadIdx.x;
  const int j = gtid >> 6;
  const int lane = threadIdx.x & 63;
  float4 v = *(const float4*)(emb + (long)j * 256 + (lane << 2));
  float s = v.x * v.x + v.y * v.y + v.z * v.z + v.w * v.w;
#pragma unroll
  for (int off = 1; off < 64; off <<= 1) s += __shfl_xor(s, off, 64);
  if (lane == 0) enorm[j] = s;
}

#define BM 128
#define BK 32

enum { EPI_NONE = 0, EPI_RELU = 1, EPI_SIGMOID = 2 };
// OMODE: 0 = fp32 out, 1 = hi/mid split out, 2 = both
// TN: per-wave tn count; BN = TN*32 (waves 2x2; wave tile 64 x TN*16)

template <int EPI, bool INDIRECT, bool ASPLIT, int OMODE, int TN>
__global__ __launch_bounds__(256, 2) void mfma_gemm(
    const float* __restrict__ Af, const unsigned short* __restrict__ Ahg,
    const unsigned short* __restrict__ Amg, const unsigned short* __restrict__ Bhi,
    const unsigned short* __restrict__ Bmid, const float* __restrict__ bias,
    float* __restrict__ Cf, unsigned short* __restrict__ Ohi,
    unsigned short* __restrict__ Omid, const int* __restrict__ aidx,
    int M, int N, int K, int Nreal) {
  constexpr int BN = TN * 32;
  constexpr int BPW = BN / 64;  // B slots per wave (16-row slots): 2 or 1
  __shared__ __align__(16) unsigned short Ah[2][BM][BK], Am[2][BM][BK];
  __shared__ __align__(16) unsigned short Bh[2][BN][BK], Bm[2][BN][BK];

  const int tid = threadIdx.x, lane = tid & 63, wave = tid >> 6;
  const int wm = wave >> 1, wn = wave & 1;
  const int row0 = blockIdx.y * BM, col0 = blockIdx.x * BN;
  const int kshort = (lane & 3) * 8;

  const unsigned short *aH[2], *aM2[2], *bH[BPW], *bM2[BPW];
  const float* aF[4];
  if (ASPLIT) {
#pragma unroll
    for (int j = 0; j < 2; j++) {
      const int rl = (wave * 2 + j) * 16 + (lane >> 2);
      const long ar = INDIRECT ? (long)aidx[row0 + rl] : (long)(row0 + rl);
      aH[j] = Ahg + ar * K + kshort;
      aM2[j] = Amg + ar * K + kshort;
    }
  } else {
#pragma unroll
    for (int i = 0; i < 4; i++)
      aF[i] = Af + (long)(row0 + i * 32 + (tid >> 3)) * K + (tid & 7) * 4;
  }
#pragma unroll
  for (int j = 0; j < BPW; j++) {
    const int rl = (wave * BPW + j) * 16 + (lane >> 2);
    bH[j] = Bhi + (long)(col0 + rl) * K + kshort;
    bM2[j] = Bmid + (long)(col0 + rl) * K + kshort;
  }

  auto stage = [&](int k0, int b) {
#pragma unroll
    for (int j = 0; j < BPW; j++) {
      const int slot = wave * BPW + j;
      glds16(bH[j] + k0, &Bh[b][0][0] + slot * 512);
      glds16(bM2[j] + k0, &Bm[b][0][0] + slot * 512);
    }
    if (ASPLIT) {
#pragma unroll
      for (int j = 0; j < 2; j++) {
        const int slot = wave * 2 + j;
        glds16(aH[j] + k0, &Ah[b][0][0] + slot * 512);
        glds16(aM2[j] + k0, &Am[b][0][0] + slot * 512);
      }
    } else {
      float4 areg[4];
#pragma unroll
      for (int i = 0; i < 4; i++) areg[i] = *(const float4*)(aF[i] + k0);
#pragma unroll
      for (int i = 0; i < 4; i++) {
        const int r = i * 32 + (tid >> 3), q4 = (tid & 7) * 4;
        ushort4v h, m;
        h.x = f2bf(areg[i].x); m.x = f2bf(areg[i].x - bf2f(h.x));
        h.y = f2bf(areg[i].y); m.y = f2bf(areg[i].y - bf2f(h.y));
        h.z = f2bf(areg[i].z); m.z = f2bf(areg[i].z - bf2f(h.z));
        h.w = f2bf(areg[i].w); m.w = f2bf(areg[i].w - bf2f(h.w));
        *(ushort4v*)&Ah[b][r][q4] = h;
        *(ushort4v*)&Am[b][r][q4] = m;
      }
    }
  };

  floatx4 acc[4][TN];
#pragma unroll
  for (int i = 0; i < 4; i++)
#pragma unroll
    for (int j = 0; j < TN; j++) acc[i][j] = (floatx4)0.f;

  stage(0, 0);  // prologue (no readers yet; first barrier drains it)
  int buf = 0;
  for (int k0 = 0; k0 < K; k0 += BK) {
    __syncthreads();  // cur-buf staging complete; prev-buf reads complete
    if (k0 + BK < K) stage(k0 + BK, buf ^ 1);  // hidden behind compute below

    short8 ah[4], am[4];
#pragma unroll
    for (int tm = 0; tm < 4; tm++) {
      const int rr = wm * 64 + tm * 16 + (lane & 15);
      const int kk = (lane >> 4) * 8;
      ah[tm] = *(const short8*)&Ah[buf][rr][kk];
      am[tm] = *(const short8*)&Am[buf][rr][kk];
    }
#pragma unroll
    for (int tn = 0; tn < TN; tn++) {
      const int rr = wn * (TN * 16) + tn * 16 + (lane & 15);
      const int kk = (lane >> 4) * 8;
      short8 bh = *(const short8*)&Bh[buf][rr][kk];
      short8 bm = *(const short8*)&Bm[buf][rr][kk];
#pragma unroll
      for (int tm = 0; tm < 4; tm++) {
        acc[tm][tn] = __builtin_amdgcn_mfma_f32_16x16x32_bf16(ah[tm], bh, acc[tm][tn], 0, 0, 0);
        acc[tm][tn] = __builtin_amdgcn_mfma_f32_16x16x32_bf16(ah[tm], bm, acc[tm][tn], 0, 0, 0);
        acc[tm][tn] = __builtin_amdgcn_mfma_f32_16x16x32_bf16(am[tm], bh, acc[tm][tn], 0, 0, 0);
      }
    }
    buf ^= 1;
  }

  const int qd = lane >> 4, ln = lane & 15;
#pragma unroll
  for (int tn = 0; tn < TN; tn++) {
    const int c = col0 + wn * (TN * 16) + tn * 16 + ln;
    const float bb = (c < Nreal) ? bias[c] : 0.f;
#pragma unroll
    for (int tm = 0; tm < 4; tm++) {
#pragma unroll
      for (int reg = 0; reg < 4; reg++) {
        const int r = row0 + wm * 64 + tm * 16 + qd * 4 + reg;
        float v = acc[tm][tn][reg] + bb;
        if (EPI == EPI_RELU) v = fmaxf(v, 0.f);
        if (EPI == EPI_SIGMOID) v = 1.f / (1.f + __expf(-v));
        if (OMODE == 0 || OMODE == 2) Cf[(long)r * N + c] = v;
        if (OMODE == 1 || OMODE == 2) {
          unsigned short h = f2bf(v);
          Ohi[(long)r * N + c] = h;
          Omid[(long)r * N + c] = f2bf(v - bf2f(h));
        }
      }
    }
  }
}

// dist candidates: grid (4, M/128); flattened 32-iteration loop over
// (chunk 0..3) x (k0 0..7), double-buffered with cross-chunk prefetch.
__global__ __launch_bounds__(256, 2) void dist_topk(
    const unsigned short* __restrict__ Zh, const unsigned short* __restrict__ Zm,
    const unsigned short* __restrict__ Eh, const unsigned short* __restrict__ Em,
    const float* __restrict__ enorm, int* __restrict__ pidx, int M) {
  const int K = 256;
  __shared__ __align__(16) unsigned short Ah[2][BM][BK], Am[2][BM][BK];
  __shared__ __align__(16) unsigned short Bh[2][BM][BK], Bm[2][BM][BK];
  __shared__ unsigned r1s[2][BM], r2s[2][BM], r3s[2][BM];

  const int tid = threadIdx.x, lane = tid & 63, wave = tid >> 6;
  const int wm = wave >> 1, wn = wave & 1;
  const int row0 = blockIdx.y * BM;
  const int col_base = blockIdx.x * 512;
  const int kshort = (lane & 3) * 8;

  const unsigned short *aH[2], *aM2[2];
  int rlj[2];
#pragma unroll
  for (int j = 0; j < 2; j++) {
    rlj[j] = (wave * 2 + j) * 16 + (lane >> 2);
    aH[j] = Zh + (long)(row0 + rlj[j]) * K + kshort;
    aM2[j] = Zm + (long)(row0 + rlj[j]) * K + kshort;
  }

  auto stage = [&](int it, int b) {
    const int k0 = (it & 7) << 5;
    const int col0 = col_base + (it >> 3) * 128;
#pragma unroll
    for (int j = 0; j < 2; j++) {
      const int slot = wave * 2 + j;
      glds16(aH[j] + k0, &Ah[b][0][0] + slot * 512);
      glds16(aM2[j] + k0, &Am[b][0][0] + slot * 512);
      glds16(Eh + (long)(col0 + rlj[j]) * K + kshort + k0, &Bh[b][0][0] + slot * 512);
      glds16(Em + (long)(col0 + rlj[j]) * K + kshort + k0, &Bm[b][0][0] + slot * 512);
    }
  };

  unsigned k1[16], k2[16], k3[16];
#pragma unroll
  for (int s = 0; s < 16; s++) { k1[s] = 0xFFFFFFFFu; k2[s] = 0xFFFFFFFFu; k3[s] = 0xFFFFFFFFu; }

  floatx4 acc[4][4];
#pragma unroll
  for (int i = 0; i < 4; i++)
#pragma unroll
    for (int j = 0; j < 4; j++) acc[i][j] = (floatx4)0.f;

  stage(0, 0);
  int buf = 0;
  for (int it = 0; it < 32; it++) {
    __syncthreads();
    if (it + 1 < 32) stage(it + 1, buf ^ 1);

    short8 ah[4], am[4];
#pragma unroll
    for (int tm = 0; tm < 4; tm++) {
      const int rr = wm * 64 + tm * 16 + (lane & 15);
      const int kk = (lane >> 4) * 8;
      ah[tm] = *(const short8*)&Ah[buf][rr][kk];
      am[tm] = *(const short8*)&Am[buf][rr][kk];
    }
#pragma unroll
    for (int tn = 0; tn < 4; tn++) {
      const int rr = wn * 64 + tn * 16 + (lane & 15);
      const int kk = (lane >> 4) * 8;
      short8 bh = *(const short8*)&Bh[buf][rr][kk];
      short8 bm = *(const short8*)&Bm[buf][rr][kk];
#pragma unroll
      for (int tm = 0; tm < 4; tm++) {
        acc[tm][tn] = __builtin_amdgcn_mfma_f32_16x16x32_bf16(ah[tm], bh, acc[tm][tn], 0, 0, 0);
        acc[tm][tn] = __builtin_amdgcn_mfma_f32_16x16x32_bf16(ah[tm], bm, acc[tm][tn], 0, 0, 0);
        acc[tm][tn] = __builtin_amdgcn_mfma_f32_16x16x32_bf16(am[tm], bh, acc[tm][tn], 0, 0, 0);
      }
    }

    if ((it & 7) == 7) {  // chunk complete: fold into top-3, reset acc
      const int col0 = col_base + (it >> 3) * 128;
#pragma unroll
      for (int tn = 0; tn < 4; tn++) {
        const int c = col0 + wn * 64 + tn * 16 + (lane & 15);
        const float en = enorm[c];
#pragma unroll
        for (int tm = 0; tm < 4; tm++)
#pragma unroll
          for (int reg = 0; reg < 4; reg++) {
            float d = en - 2.f * acc[tm][tn][reg];
            ins3(packkey(d, c), k1[tm * 4 + reg], k2[tm * 4 + reg], k3[tm * 4 + reg]);
          }
      }
#pragma unroll
      for (int i = 0; i < 4; i++)
#pragma unroll
        for (int j = 0; j < 4; j++) acc[i][j] = (floatx4)0.f;
    }
    buf ^= 1;
  }

#pragma unroll
  for (int s = 0; s < 16; s++) {
#pragma unroll
    for (int off = 1; off < 16; off <<= 1) {
      unsigned o1 = __shfl_xor(k1[s], off, 64);
      unsigned o2 = __shfl_xor(k2[s], off, 64);
      unsigned o3 = __shfl_xor(k3[s], off, 64);
      ins3(o1, k1[s], k2[s], k3[s]);
      ins3(o2, k1[s], k2[s], k3[s]);
      ins3(o3, k1[s], k2[s], k3[s]);
    }
  }
  if ((lane & 15) == 0) {
#pragma unroll
    for (int s = 0; s < 16; s++) {
      int rl = wm * 64 + (s >> 2) * 16 + (lane >> 4) * 4 + (s & 3);
      r1s[wn][rl] = k1[s]; r2s[wn][rl] = k2[s]; r3s[wn][rl] = k3[s];
    }
  }
  __syncthreads();
  if (tid < BM) {
    unsigned v1 = r1s[0][tid], v2 = r2s[0][tid], v3 = r3s[0][tid];
    ins3(r1s[1][tid], v1, v2, v3);
    ins3(r2s[1][tid], v1, v2, v3);
    ins3(r3s[1][tid], v1, v2, v3);
    const long base = ((long)blockIdx.x * M + (row0 + tid)) * 4;
    pidx[base + 0] = (int)(v1 & 0x7FFu);
    pidx[base + 1] = (int)(v2 & 0x7FFu);
    pidx[base + 2] = (int)(v3 & 0x7FFu);
  }
}

// exact fp32 rescore of 12 candidates/row; one wave per row
__global__ __launch_bounds__(256) void rescore(
    const float* __restrict__ z, const float* __restrict__ emb,
    const float* __restrict__ enorm, const int* __restrict__ pidx,
    int* __restrict__ idx, int M) {
  const int wave = threadIdx.x >> 6, lane = threadIdx.x & 63;
  const int r = blockIdx.x * 4 + wave;
  float4 zv = *(const float4*)(z + (long)r * 256 + lane * 4);
  float best = FLT_MAX;
  int bi = 0x7fffffff;
#pragma unroll
  for (int g = 0; g < 4; g++) {
#pragma unroll
    for (int s = 0; s < 3; s++) {
      const int j = pidx[((long)g * M + r) * 4 + s];
      float4 ev = *(const float4*)(emb + (long)j * 256 + lane * 4);
      float t = zv.x * ev.x + zv.y * ev.y + zv.z * ev.z + zv.w * ev.w;
#pragma unroll
      for (int off = 1; off < 64; off <<= 1) t += __shfl_xor(t, off, 64);
      const float d = enorm[j] - 2.f * t;
      if (d < best || (d == best && j < bi)) { best = d; bi = j; }
    }
  }
  if (lane == 0) idx[r] = bi;
}

extern "C" void kernel_launch(void* const* d_in, const int* in_sizes, int n_in,
                              void* d_out, int out_size, void* d_ws, size_t ws_size,
                              hipStream_t stream) {
  const float* x   = (const float*)d_in[0];
  const float* W1  = (const float*)d_in[1];
  const float* b1  = (const float*)d_in[2];
  const float* W2  = (const float*)d_in[3];
  const float* b2  = (const float*)d_in[4];
  const float* W3  = (const float*)d_in[5];
  const float* b3  = (const float*)d_in[6];
  const float* W4  = (const float*)d_in[7];
  const float* b4  = (const float*)d_in[8];
  const float* emb = (const float*)d_in[9];
  float* out = (float*)d_out;

  const int BZ = 16384, IN = 1024, H = 400, Hp = 512, D = 256, NE = 2048;

  char* ws = (char*)d_ws;
  size_t off = 0;
  auto alloc = [&](size_t bytes) {
    void* p = ws + off;
    off += (bytes + 255) & ~(size_t)255;
    return p;
  };
  unsigned short* w1h = (unsigned short*)alloc((size_t)Hp * IN * 2);
  unsigned short* w1m = (unsigned short*)alloc((size_t)Hp * IN * 2);
  unsigned short* w2h = (unsigned short*)alloc((size_t)D * Hp * 2);
  unsigned short* w2m = (unsigned short*)alloc((size_t)D * Hp * 2);
  unsigned short* w3h = (unsigned short*)alloc((size_t)Hp * D * 2);
  unsigned short* w3m = (unsigned short*)alloc((size_t)Hp * D * 2);
  unsigned short* w4h = (unsigned short*)alloc((size_t)IN * Hp * 2);
  unsigned short* w4m = (unsigned short*)alloc((size_t)IN * Hp * 2);
  unsigned short* eh  = (unsigned short*)alloc((size_t)NE * D * 2);
  unsigned short* em  = (unsigned short*)alloc((size_t)NE * D * 2);
  float* enorm = (float*)alloc((size_t)NE * 4);
  unsigned short* h1h = (unsigned short*)alloc((size_t)BZ * Hp * 2);  // 16MB
  unsigned short* h1m = (unsigned short*)alloc((size_t)BZ * Hp * 2);  // 16MB
  float* zf = (float*)alloc((size_t)BZ * D * 4);                       // 16MB
  unsigned short* zh = (unsigned short*)alloc((size_t)BZ * D * 2);     // 8MB
  unsigned short* zm = (unsigned short*)alloc((size_t)BZ * D * 2);     // 8MB
  // aliases (lifetimes disjoint on the sequential stream):
  unsigned short* h3h = (unsigned short*)zf;   // zf dead after rescore
  unsigned short* h3m = zh;                    // zh+zm dead after dist
  int* pidx = (int*)h1h;                       // h1 dead after GEMM2
  int* idx  = ((int*)h1h) + (size_t)4 * BZ * 4;

  conv_pad<<<dim3((Hp * IN + 255) / 256), dim3(256), 0, stream>>>(W1, w1h, w1m, H, IN, Hp, IN);
  conv_pad<<<dim3((D * Hp + 255) / 256), dim3(256), 0, stream>>>(W2, w2h, w2m, D, H, D, Hp);
  conv_pad<<<dim3((Hp * D + 255) / 256), dim3(256), 0, stream>>>(W3, w3h, w3m, H, D, Hp, D);
  conv_pad<<<dim3((IN * Hp + 255) / 256), dim3(256), 0, stream>>>(W4, w4h, w4m, IN, H, IN, Hp);
  conv_pad<<<dim3((NE * D + 255) / 256), dim3(256), 0, stream>>>(emb, eh, em, NE, D, NE, D);
  emb_norm<<<dim3(NE * 64 / 256), dim3(256), 0, stream>>>(emb, enorm);

  // h1 = relu(x @ W1^T + b1) -> hi/mid [BZ][512]
  mfma_gemm<EPI_RELU, false, false, 1, 4><<<dim3(Hp / 128, BZ / BM), dim3(256), 0, stream>>>(
      x, nullptr, nullptr, w1h, w1m, b1, nullptr, h1h, h1m, nullptr, BZ, Hp, IN, H);
  // z_e = h1 @ W2^T + b2 -> fp32 + hi/mid [BZ][256]  (BN=64: 512 blocks)
  mfma_gemm<EPI_NONE, false, true, 2, 2><<<dim3(D / 64, BZ / BM), dim3(256), 0, stream>>>(
      nullptr, h1h, h1m, w2h, w2m, b2, zf, zh, zm, nullptr, BZ, D, Hp, D);
  // dist candidates: top-3 per 512-col group
  dist_topk<<<dim3(4, BZ / BM), dim3(256), 0, stream>>>(zh, zm, eh, em, enorm, pidx, BZ);
  // exact fp32 rescore -> idx
  rescore<<<dim3(BZ / 4), dim3(256), 0, stream>>>(zf, emb, enorm, pidx, idx, BZ);
  // h3 = relu(emb[idx] @ W3^T + b3) -> hi/mid [BZ][512]
  mfma_gemm<EPI_RELU, true, true, 1, 4><<<dim3(Hp / 128, BZ / BM), dim3(256), 0, stream>>>(
      nullptr, eh, em, w3h, w3m, b3, nullptr, h3h, h3m, idx, BZ, Hp, D, H);
  // out = sigmoid(h3 @ W4^T + b4) -> fp32 [BZ][1024]
  mfma_gemm<EPI_SIGMOID, false, true, 0, 4><<<dim3(IN / 128, BZ / BM), dim3(256), 0, stream>>>(
      nullptr, h3h, h3m, w4h, w4m, b4, out, nullptr, nullptr, nullptr, BZ, IN, Hp, IN);
}